// Round 2
// baseline (392.000 us; speedup 1.0000x reference)
//
#include <hip/hip_runtime.h>
#include <stdint.h>

#define B_ 4
#define S_ 2048
#define H_ 16
#define D_ 64
#define E_ 1024

typedef __bf16 bf16x8 __attribute__((ext_vector_type(8)));
typedef float f32x4 __attribute__((ext_vector_type(4)));
typedef unsigned short u16x4 __attribute__((ext_vector_type(4)));

static __device__ __forceinline__ unsigned short f2bf(float f) {
    unsigned u = __builtin_bit_cast(unsigned, f);
    u += 0x7fffu + ((u >> 16) & 1u);
    return (unsigned short)(u >> 16);
}

static __device__ __forceinline__ f32x4 mfma16(bf16x8 a, bf16x8 b, f32x4 c) {
    return __builtin_amdgcn_mfma_f32_16x16x32_bf16(a, b, c, 0, 0, 0);
}

static __device__ __forceinline__ void gload_lds16(const void* g, void* l) {
    __builtin_amdgcn_global_load_lds(
        (__attribute__((address_space(1))) void*)g,
        (__attribute__((address_space(3))) void*)l, 16, 0, 0);
}

// ---------------- fp32 -> bf16 convert ----------------
__global__ void cvt_f32_bf16_k(const float* __restrict__ src,
                               unsigned short* __restrict__ dst, int n4) {
    int stride = gridDim.x * blockDim.x;
    for (int i = blockIdx.x * blockDim.x + threadIdx.x; i < n4; i += stride) {
        float4 v = reinterpret_cast<const float4*>(src)[i];
        u16x4 o;
        o[0] = f2bf(v.x); o[1] = f2bf(v.y); o[2] = f2bf(v.z); o[3] = f2bf(v.w);
        reinterpret_cast<u16x4*>(dst)[i] = o;
    }
}

// ---------------- QKV projection GEMM (m97 structure) + fused RoPE/l2norm epilogue ----------------
// C[m][o] = sum_e x[m][e] * W[o][e];  M=8192, N=3072, K=1024.
// Epilogue: cols 0..1023 -> Q (rope+norm+sqk*32*0.125) -> (B,H,S,D) bf16
//           cols 1024..2047 -> K (rope+norm+sqk*32)    -> (B,H,S,D) bf16
//           cols 2048..3071 -> V (raw)                 -> (B,H,D,S) bf16 (transposed)
__global__ __launch_bounds__(256) void qkv_gemm_k(
    const unsigned short* __restrict__ xbf,
    const unsigned short* __restrict__ wbf,
    const float* __restrict__ sqk,
    const float* __restrict__ fcos,
    const float* __restrict__ fsin,
    unsigned short* __restrict__ qws,
    unsigned short* __restrict__ kws,
    unsigned short* __restrict__ vtws)
{
    __shared__ unsigned short As[128 * 32];
    __shared__ unsigned short Bs[128 * 32];
    const int tid = threadIdx.x;
    const int w = tid >> 6, lane = tid & 63;
    const int wr = w >> 1, wc = w & 1;
    const int mbase = blockIdx.y * 128;
    const int nbase = blockIdx.x * 128;
    const int c15 = lane & 15;
    const int g4 = lane >> 4;
    const int kb8 = g4 * 8;

    const f32x4 zero4 = {0.f, 0.f, 0.f, 0.f};
    f32x4 acc[4][4];
#pragma unroll
    for (int m = 0; m < 4; m++)
#pragma unroll
        for (int n = 0; n < 4; n++) acc[m][n] = zero4;

    for (int kt = 0; kt < 32; ++kt) {
        const int k0 = kt * 32;
#pragma unroll
        for (int i = 0; i < 2; i++) {
            int g = (i * 4 + w) * 64 + lane;
            int row = g >> 2, slot = g & 3;
            gload_lds16(xbf + (size_t)(mbase + row) * E_ + k0 + slot * 8,
                        As + (i * 4 + w) * 512);
            gload_lds16(wbf + (size_t)(nbase + row) * E_ + k0 + slot * 8,
                        Bs + (i * 4 + w) * 512);
        }
        asm volatile("s_waitcnt vmcnt(0)" ::: "memory");
        __syncthreads();
        bf16x8 af[4], bfr[4];
#pragma unroll
        for (int m = 0; m < 4; m++)
            af[m] = *(const bf16x8*)(As + (wr * 64 + m * 16 + c15) * 32 + kb8);
#pragma unroll
        for (int n = 0; n < 4; n++)
            bfr[n] = *(const bf16x8*)(Bs + (wc * 64 + n * 16 + c15) * 32 + kb8);
#pragma unroll
        for (int m = 0; m < 4; m++)
#pragma unroll
            for (int n = 0; n < 4; n++)
                acc[m][n] = mfma16(af[m], bfr[n], acc[m][n]);
        __syncthreads();
    }

    // ---- epilogue ----
    const int gcb = nbase + wc * 64;  // 64-aligned output column base
    const int qkv = gcb >> 10;
    const int oo = gcb & 1023;
    const int h = oo >> 6;

    if (qkv < 2) {
        unsigned short* dst = (qkv == 0) ? qws : kws;
        const float qs = (qkv == 0) ? 0.125f : 1.0f;  // fold D^-0.5 into Q
        float cs4[4];
#pragma unroll
        for (int n = 0; n < 4; n++)
            cs4[n] = sqk[oo + n * 16 + c15] * 32.0f * qs;
#pragma unroll
        for (int m = 0; m < 4; m++) {
#pragma unroll
            for (int r = 0; r < 4; r++) {
                const int grow = mbase + wr * 64 + m * 16 + g4 * 4 + r;
                const int bb = grow >> 11;
                const int srow = grow & 2047;
                float nv[4], ss = 0.f;
#pragma unroll
                for (int n = 0; n < 4; n++) {
                    const int d = n * 16 + c15;
                    const float a = acc[m][n][r];
                    const float other = __shfl_xor(a, 1);
                    const float cc = fcos[srow * 32 + (d >> 1)];
                    const float sn = fsin[srow * 32 + (d >> 1)];
                    // even d: a*cos - b*sin ; odd d: a*sin + b*cos (a=even elem, b=odd elem)
                    const float rv = (d & 1) ? (other * sn + a * cc) : (a * cc - other * sn);
                    nv[n] = rv;
                    ss += rv * rv;
                }
#pragma unroll
                for (int mask = 1; mask < 16; mask <<= 1)
                    ss += __shfl_xor(ss, mask);
                const float rn = rsqrtf(ss);
                unsigned short* rp = dst + ((size_t)(bb * H_ + h) * S_ + srow) * D_;
#pragma unroll
                for (int n = 0; n < 4; n++)
                    rp[n * 16 + c15] = f2bf(nv[n] * rn * cs4[n]);
            }
        }
    } else {
        // V: write transposed (B,H,D,S); 4 consecutive s rows pack into one 8B store
#pragma unroll
        for (int m = 0; m < 4; m++) {
            const int grow0 = mbase + wr * 64 + m * 16 + g4 * 4;
            const int bb = grow0 >> 11;
            const int srow0 = grow0 & 2047;
#pragma unroll
            for (int n = 0; n < 4; n++) {
                const int d = n * 16 + c15;
                u16x4 pk;
#pragma unroll
                for (int r = 0; r < 4; r++) pk[r] = f2bf(acc[m][n][r]);
                *reinterpret_cast<u16x4*>(vtws + ((size_t)(bb * H_ + h) * D_ + d) * S_ + srow0) = pk;
            }
        }
    }
}

// ---------------- flash attention ----------------
// grid: (S/64, B*H). 4 waves, wave w owns q rows [q0+w*16, q0+w*16+16).
// K tile [kv][d] and V^T tile [d][kv] staged via global_load_lds with
// XOR-swizzled SOURCE addresses (byte ^= ((row&7)<<4) within 128B rows);
// reads apply the same swizzle -> conflict-free ds_read_b128.
__global__ __launch_bounds__(256) void attn_fwd_k(
    const unsigned short* __restrict__ qws,
    const unsigned short* __restrict__ kws,
    const unsigned short* __restrict__ vtws,
    float* __restrict__ out)
{
    __shared__ unsigned short Klds[64 * 64];
    __shared__ unsigned short Vlds[64 * 64];
    __shared__ unsigned short Plds[64 * 72];  // +8 pad: de-conflict scalar P writes
    const int tid = threadIdx.x;
    const int w = tid >> 6, lane = tid & 63;
    const int c15 = lane & 15;
    const int g4 = lane >> 4;
    const int kb8 = g4 * 8;
    const int bh = blockIdx.y;
    const int b = bh >> 4, h = bh & 15;
    const int q0 = blockIdx.x * 64;

    bf16x8 qf[2];
    {
        const unsigned short* qp =
            qws + ((size_t)bh * S_ + (q0 + w * 16 + c15)) * D_ + kb8;
        qf[0] = *(const bf16x8*)qp;
        qf[1] = *(const bf16x8*)(qp + 32);
    }

    const f32x4 zero4 = {0.f, 0.f, 0.f, 0.f};
    float mrow[4], lrow[4];
    f32x4 o[4];
#pragma unroll
    for (int n = 0; n < 4; n++) o[n] = zero4;
#pragma unroll
    for (int r = 0; r < 4; r++) { mrow[r] = -3.0e38f; lrow[r] = 0.f; }

    const char* kbase_g = (const char*)(kws + (size_t)bh * S_ * D_);
    const unsigned short* vbase_g = vtws + (size_t)bh * D_ * S_;

    for (int kt = 0; kt < 32; ++kt) {
        // stage K tile (contiguous 8KB) with pre-swizzled source
#pragma unroll
        for (int i = 0; i < 2; i++) {
            int loff = ((i * 4 + w) * 64 + lane) * 16;
            int soff = loff ^ (((loff >> 7) & 7) << 4);
            gload_lds16(kbase_g + (size_t)kt * 8192 + soff,
                        (char*)Klds + (i * 4 + w) * 1024);
        }
        // stage V^T tile: 64 rows (d) x 128B, row stride S*2 in global
#pragma unroll
        for (int i = 0; i < 2; i++) {
            int g = (i * 4 + w) * 64 + lane;
            int row = g >> 3, slot = g & 7;
            int soff = (slot * 16) ^ ((row & 7) << 4);
            gload_lds16((const char*)(vbase_g + (size_t)row * S_ + kt * 64) + soff,
                        (char*)Vlds + (i * 4 + w) * 1024);
        }
        asm volatile("s_waitcnt vmcnt(0)" ::: "memory");
        __syncthreads();

        // ---- QK^T : s[n] covers kv cols n*16+c15 ----
        f32x4 sf[4];
#pragma unroll
        for (int n = 0; n < 4; n++) {
            sf[n] = zero4;
            const int kvc = n * 16 + c15;
            const char* kro = (const char*)Klds + kvc * 128;
            const int sw = (kvc & 7) << 4;
            sf[n] = mfma16(qf[0], *(const bf16x8*)(kro + ((kb8 * 2) ^ sw)), sf[n]);
            sf[n] = mfma16(qf[1], *(const bf16x8*)(kro + ((kb8 * 2 + 64) ^ sw)), sf[n]);
        }

        // ---- online softmax (rows = g4*4+r, cols across c15 lanes + n frags) ----
        float mn[4];
#pragma unroll
        for (int r = 0; r < 4; r++)
            mn[r] = fmaxf(fmaxf(sf[0][r], sf[1][r]), fmaxf(sf[2][r], sf[3][r]));
#pragma unroll
        for (int mask = 1; mask < 16; mask <<= 1)
#pragma unroll
            for (int r = 0; r < 4; r++)
                mn[r] = fmaxf(mn[r], __shfl_xor(mn[r], mask));
        float alpha[4];
#pragma unroll
        for (int r = 0; r < 4; r++) {
            float mt = fmaxf(mrow[r], mn[r]);
            alpha[r] = __expf(mrow[r] - mt);
            mrow[r] = mt;
        }
        float rs[4] = {0.f, 0.f, 0.f, 0.f};
#pragma unroll
        for (int n = 0; n < 4; n++)
#pragma unroll
            for (int r = 0; r < 4; r++) {
                float p = __expf(sf[n][r] - mrow[r]);
                sf[n][r] = p;
                rs[r] += p;
            }
#pragma unroll
        for (int mask = 1; mask < 16; mask <<= 1)
#pragma unroll
            for (int r = 0; r < 4; r++)
                rs[r] += __shfl_xor(rs[r], mask);
#pragma unroll
        for (int r = 0; r < 4; r++)
            lrow[r] = lrow[r] * alpha[r] + rs[r];
#pragma unroll
        for (int n = 0; n < 4; n++)
#pragma unroll
            for (int r = 0; r < 4; r++)
                o[n][r] *= alpha[r];

        // ---- P -> LDS (per-wave private region; no cross-wave sharing) ----
        {
            const int pr0 = w * 16 + g4 * 4;
#pragma unroll
            for (int n = 0; n < 4; n++) {
                const int pc = n * 16 + c15;
#pragma unroll
                for (int r = 0; r < 4; r++)
                    Plds[(pr0 + r) * 72 + pc] = f2bf(sf[n][r]);
            }
        }
        asm volatile("s_waitcnt lgkmcnt(0)" ::: "memory");

        // ---- PV ----
        bf16x8 pf[2];
        {
            const unsigned short* pp = Plds + (w * 16 + c15) * 72 + kb8;
            pf[0] = *(const bf16x8*)pp;
            pf[1] = *(const bf16x8*)(pp + 32);
        }
#pragma unroll
        for (int n = 0; n < 4; n++) {
            const int dc = n * 16 + c15;
            const char* vro = (const char*)Vlds + dc * 128;
            const int sw = (dc & 7) << 4;
            o[n] = mfma16(pf[0], *(const bf16x8*)(vro + ((kb8 * 2) ^ sw)), o[n]);
            o[n] = mfma16(pf[1], *(const bf16x8*)(vro + ((kb8 * 2 + 64) ^ sw)), o[n]);
        }
        __syncthreads();
    }

    // ---- epilogue: out (B,S,H*D) fp32 ----
    const int so0 = q0 + w * 16 + g4 * 4;
#pragma unroll
    for (int r = 0; r < 4; r++) {
        const float inv = 1.0f / lrow[r];
        float* op = out + ((size_t)b * S_ + so0 + r) * E_ + h * D_;
#pragma unroll
        for (int n = 0; n < 4; n++)
            op[n * 16 + c15] = o[n][r] * inv;
    }
}

extern "C" void kernel_launch(void* const* d_in, const int* in_sizes, int n_in,
                              void* d_out, int out_size, void* d_ws, size_t ws_size,
                              hipStream_t stream) {
    (void)in_sizes; (void)n_in; (void)out_size; (void)ws_size;
    const float* x = (const float*)d_in[0];
    const float* Wq = (const float*)d_in[1];
    const float* Wk = (const float*)d_in[2];
    const float* Wv = (const float*)d_in[3];
    const float* sqk = (const float*)d_in[4];
    const float* fcos = (const float*)d_in[5];
    const float* fsin = (const float*)d_in[6];

    char* ws = (char*)d_ws;
    size_t off = 0;
    unsigned short* xbf = (unsigned short*)(ws + off); off += (size_t)B_ * S_ * E_ * 2;   // 16 MiB
    unsigned short* wbf = (unsigned short*)(ws + off); off += (size_t)3 * E_ * E_ * 2;    // 6 MiB
    unsigned short* qws = (unsigned short*)(ws + off); off += (size_t)B_ * H_ * S_ * D_ * 2;
    unsigned short* kws = (unsigned short*)(ws + off); off += (size_t)B_ * H_ * S_ * D_ * 2;
    unsigned short* vtws = (unsigned short*)(ws + off); off += (size_t)B_ * H_ * S_ * D_ * 2;

    cvt_f32_bf16_k<<<dim3(2048), dim3(256), 0, stream>>>(x, xbf, (B_ * S_ * E_) / 4);
    cvt_f32_bf16_k<<<dim3(512), dim3(256), 0, stream>>>(Wq, wbf, (E_ * E_) / 4);
    cvt_f32_bf16_k<<<dim3(512), dim3(256), 0, stream>>>(Wk, wbf + E_ * E_, (E_ * E_) / 4);
    cvt_f32_bf16_k<<<dim3(512), dim3(256), 0, stream>>>(Wv, wbf + 2 * E_ * E_, (E_ * E_) / 4);

    qkv_gemm_k<<<dim3(24, 64), dim3(256), 0, stream>>>(xbf, wbf, sqk, fcos, fsin,
                                                       qws, kws, vtws);
    attn_fwd_k<<<dim3(32, 64), dim3(256), 0, stream>>>(qws, kws, vtws, (float*)d_out);
}

// Round 4
// 356.184 us; speedup vs baseline: 1.1006x; 1.1006x over previous
//
#include <hip/hip_runtime.h>
#include <stdint.h>

#define B_ 4
#define S_ 2048
#define H_ 16
#define D_ 64
#define E_ 1024

typedef __bf16 bf16x8 __attribute__((ext_vector_type(8)));
typedef float f32x4 __attribute__((ext_vector_type(4)));
typedef unsigned short u16x4 __attribute__((ext_vector_type(4)));

static __device__ __forceinline__ unsigned short f2bf(float f) {
    unsigned u = __builtin_bit_cast(unsigned, f);
    u += 0x7fffu + ((u >> 16) & 1u);
    return (unsigned short)(u >> 16);
}

static __device__ __forceinline__ float fexp2(float x) {
    float r;
    asm("v_exp_f32 %0, %1" : "=v"(r) : "v"(x));
    return r;
}

static __device__ __forceinline__ unsigned cvtpk_bf16(float lo, float hi) {
    unsigned r;
    asm("v_cvt_pk_bf16_f32 %0, %1, %2" : "=v"(r) : "v"(lo), "v"(hi));
    return r;
}

static __device__ __forceinline__ f32x4 mfma16(bf16x8 a, bf16x8 b, f32x4 c) {
    return __builtin_amdgcn_mfma_f32_16x16x32_bf16(a, b, c, 0, 0, 0);
}

static __device__ __forceinline__ void gload_lds16(const void* g, void* l) {
    __builtin_amdgcn_global_load_lds(
        (__attribute__((address_space(1))) void*)g,
        (__attribute__((address_space(3))) void*)l, 16, 0, 0);
}

// ---------------- fp32 -> bf16 convert ----------------
__global__ void cvt_f32_bf16_k(const float* __restrict__ src,
                               unsigned short* __restrict__ dst, int n4) {
    int stride = gridDim.x * blockDim.x;
    for (int i = blockIdx.x * blockDim.x + threadIdx.x; i < n4; i += stride) {
        float4 v = reinterpret_cast<const float4*>(src)[i];
        u16x4 o;
        o[0] = f2bf(v.x); o[1] = f2bf(v.y); o[2] = f2bf(v.z); o[3] = f2bf(v.w);
        reinterpret_cast<u16x4*>(dst)[i] = o;
    }
}

// ---------------- QKV projection GEMM (m97 structure) + fused RoPE/l2norm epilogue ----------------
// Q gets D^-0.5 * log2(e) folded in so attention can use raw exp2.
__global__ __launch_bounds__(256) void qkv_gemm_k(
    const unsigned short* __restrict__ xbf,
    const unsigned short* __restrict__ wbf,
    const float* __restrict__ sqk,
    const float* __restrict__ fcos,
    const float* __restrict__ fsin,
    unsigned short* __restrict__ qws,
    unsigned short* __restrict__ kws,
    unsigned short* __restrict__ vtws)
{
    __shared__ unsigned short As[128 * 32];
    __shared__ unsigned short Bs[128 * 32];
    const int tid = threadIdx.x;
    const int w = tid >> 6, lane = tid & 63;
    const int wr = w >> 1, wc = w & 1;
    const int mbase = blockIdx.y * 128;
    const int nbase = blockIdx.x * 128;
    const int c15 = lane & 15;
    const int g4 = lane >> 4;
    const int kb8 = g4 * 8;

    const f32x4 zero4 = {0.f, 0.f, 0.f, 0.f};
    f32x4 acc[4][4];
#pragma unroll
    for (int m = 0; m < 4; m++)
#pragma unroll
        for (int n = 0; n < 4; n++) acc[m][n] = zero4;

    for (int kt = 0; kt < 32; ++kt) {
        const int k0 = kt * 32;
#pragma unroll
        for (int i = 0; i < 2; i++) {
            int g = (i * 4 + w) * 64 + lane;
            int row = g >> 2, slot = g & 3;
            gload_lds16(xbf + (size_t)(mbase + row) * E_ + k0 + slot * 8,
                        As + (i * 4 + w) * 512);
            gload_lds16(wbf + (size_t)(nbase + row) * E_ + k0 + slot * 8,
                        Bs + (i * 4 + w) * 512);
        }
        asm volatile("s_waitcnt vmcnt(0)" ::: "memory");
        __syncthreads();
        bf16x8 af[4], bfr[4];
#pragma unroll
        for (int m = 0; m < 4; m++)
            af[m] = *(const bf16x8*)(As + (wr * 64 + m * 16 + c15) * 32 + kb8);
#pragma unroll
        for (int n = 0; n < 4; n++)
            bfr[n] = *(const bf16x8*)(Bs + (wc * 64 + n * 16 + c15) * 32 + kb8);
        __builtin_amdgcn_s_setprio(1);
#pragma unroll
        for (int m = 0; m < 4; m++)
#pragma unroll
            for (int n = 0; n < 4; n++)
                acc[m][n] = mfma16(af[m], bfr[n], acc[m][n]);
        __builtin_amdgcn_s_setprio(0);
        __syncthreads();
    }

    // ---- epilogue ----
    const int gcb = nbase + wc * 64;
    const int qkv = gcb >> 10;
    const int oo = gcb & 1023;
    const int h = oo >> 6;

    if (qkv < 2) {
        unsigned short* dst = (qkv == 0) ? qws : kws;
        // fold D^-0.5 * log2(e) into Q so attention uses exp2 directly
        const float qs = (qkv == 0) ? (0.125f * 1.44269504f) : 1.0f;
        float cs4[4];
#pragma unroll
        for (int n = 0; n < 4; n++)
            cs4[n] = sqk[oo + n * 16 + c15] * 32.0f * qs;
#pragma unroll
        for (int m = 0; m < 4; m++) {
#pragma unroll
            for (int r = 0; r < 4; r++) {
                const int grow = mbase + wr * 64 + m * 16 + g4 * 4 + r;
                const int bb = grow >> 11;
                const int srow = grow & 2047;
                float nv[4], ss = 0.f;
#pragma unroll
                for (int n = 0; n < 4; n++) {
                    const int d = n * 16 + c15;
                    const float a = acc[m][n][r];
                    const float other = __shfl_xor(a, 1);
                    const float cc = fcos[srow * 32 + (d >> 1)];
                    const float sn = fsin[srow * 32 + (d >> 1)];
                    const float rv = (d & 1) ? (other * sn + a * cc) : (a * cc - other * sn);
                    nv[n] = rv;
                    ss += rv * rv;
                }
#pragma unroll
                for (int mask = 1; mask < 16; mask <<= 1)
                    ss += __shfl_xor(ss, mask);
                const float rn = rsqrtf(ss);
                unsigned short* rp = dst + ((size_t)(bb * H_ + h) * S_ + srow) * D_;
#pragma unroll
                for (int n = 0; n < 4; n++)
                    rp[n * 16 + c15] = f2bf(nv[n] * rn * cs4[n]);
            }
        }
    } else {
#pragma unroll
        for (int m = 0; m < 4; m++) {
            const int grow0 = mbase + wr * 64 + m * 16 + g4 * 4;
            const int bb = grow0 >> 11;
            const int srow0 = grow0 & 2047;
#pragma unroll
            for (int n = 0; n < 4; n++) {
                const int d = n * 16 + c15;
                u16x4 pk;
#pragma unroll
                for (int r = 0; r < 4; r++) pk[r] = f2bf(acc[m][n][r]);
                *reinterpret_cast<u16x4*>(vtws + ((size_t)(bb * H_ + h) * D_ + d) * S_ + srow0) = pk;
            }
        }
    }
}

// ---------------- flash attention (dbuf prefetch + defer-max + lazy sum) ----------------
// grid: flat 2048 blocks, XCD-swizzled so each XCD owns 8 consecutive bh.
// 4 waves, wave w owns 16 q rows. KV tiles of 64, double-buffered.
__global__ __launch_bounds__(256) void attn_fwd_k(
    const unsigned short* __restrict__ qws,
    const unsigned short* __restrict__ kws,
    const unsigned short* __restrict__ vtws,
    float* __restrict__ out)
{
    __shared__ unsigned short Klds[2 * 64 * 64];
    __shared__ unsigned short Vlds[2 * 64 * 64];
    __shared__ unsigned short Plds[64 * 68];  // pad 68: write banks {0,8,16,24}+c15/2, reads <=2-way
    const int tid = threadIdx.x;
    const int w = tid >> 6, lane = tid & 63;
    const int c15 = lane & 15;
    const int g4 = lane >> 4;
    const int kb8 = g4 * 8;

    // XCD-aware swizzle: 2048 blocks = 8 xcd * (8 bh * 32 qtiles)
    const int id = blockIdx.x;
    const int xcd = id & 7, c = id >> 3;
    const int bh = xcd * 8 + (c >> 5);
    const int q0 = (c & 31) * 64;
    const int b = bh >> 4, h = bh & 15;

    bf16x8 qf[2];
    {
        const unsigned short* qp =
            qws + ((size_t)bh * S_ + (q0 + w * 16 + c15)) * D_ + kb8;
        qf[0] = *(const bf16x8*)qp;
        qf[1] = *(const bf16x8*)(qp + 32);
    }

    const f32x4 zero4 = {0.f, 0.f, 0.f, 0.f};
    float mrow[4], lrow[4];
    f32x4 o[4];
#pragma unroll
    for (int n = 0; n < 4; n++) o[n] = zero4;
#pragma unroll
    for (int r = 0; r < 4; r++) { mrow[r] = -3.0e38f; lrow[r] = 0.f; }

    const char* kbase_g = (const char*)(kws + (size_t)bh * S_ * D_);
    const unsigned short* vbase_g = vtws + (size_t)bh * D_ * S_;

    auto STAGE = [&](int t, int bsel) {
#pragma unroll
        for (int i = 0; i < 2; i++) {
            int loff = ((i * 4 + w) * 64 + lane) * 16;
            int soff = loff ^ (((loff >> 7) & 7) << 4);
            gload_lds16(kbase_g + (size_t)t * 8192 + soff,
                        (char*)Klds + bsel * 8192 + (i * 4 + w) * 1024);
        }
#pragma unroll
        for (int i = 0; i < 2; i++) {
            int g = (i * 4 + w) * 64 + lane;
            int row = g >> 3, slot = g & 7;
            int soff = (slot * 16) ^ ((row & 7) << 4);
            gload_lds16((const char*)(vbase_g + (size_t)row * S_ + t * 64) + soff,
                        (char*)Vlds + bsel * 8192 + (i * 4 + w) * 1024);
        }
    };

    STAGE(0, 0);
    asm volatile("s_waitcnt vmcnt(0)" ::: "memory");
    __syncthreads();

    int cur = 0;
    for (int kt = 0; kt < 32; ++kt) {
        if (kt + 1 < 32) STAGE(kt + 1, cur ^ 1);  // prefetch next tile

        const char* kb_l = (const char*)Klds + cur * 8192;
        const char* vb_l = (const char*)Vlds + cur * 8192;

        // ---- QK^T ----
        f32x4 sf[4];
        bf16x8 kf[4][2];
#pragma unroll
        for (int n = 0; n < 4; n++) {
            const int kvc = n * 16 + c15;
            const char* kro = kb_l + kvc * 128;
            const int sw = (kvc & 7) << 4;
            kf[n][0] = *(const bf16x8*)(kro + ((kb8 * 2) ^ sw));
            kf[n][1] = *(const bf16x8*)(kro + ((kb8 * 2 + 64) ^ sw));
        }
        __builtin_amdgcn_s_setprio(1);
#pragma unroll
        for (int n = 0; n < 4; n++) {
            sf[n] = zero4;
            sf[n] = mfma16(qf[0], kf[n][0], sf[n]);
            sf[n] = mfma16(qf[1], kf[n][1], sf[n]);
        }
        __builtin_amdgcn_s_setprio(0);

        // ---- online softmax: defer-max (THR=8 in exp2 domain) ----
        float pmax[4];
#pragma unroll
        for (int r = 0; r < 4; r++)
            pmax[r] = fmaxf(fmaxf(sf[0][r], sf[1][r]), fmaxf(sf[2][r], sf[3][r]));
        int ok = (pmax[0] <= mrow[0] + 8.0f) & (pmax[1] <= mrow[1] + 8.0f) &
                 (pmax[2] <= mrow[2] + 8.0f) & (pmax[3] <= mrow[3] + 8.0f);
        if (!__all(ok)) {
            // slow path: true row max, rescale state
#pragma unroll
            for (int r = 0; r < 4; r++) {
                float mn = pmax[r];
#pragma unroll
                for (int mask = 1; mask < 16; mask <<= 1)
                    mn = fmaxf(mn, __shfl_xor(mn, mask));
                float mt = fmaxf(mrow[r], mn);
                float al = fexp2(mrow[r] - mt);
                mrow[r] = mt;
                lrow[r] *= al;
#pragma unroll
                for (int n = 0; n < 4; n++) o[n][r] *= al;
            }
        }
#pragma unroll
        for (int n = 0; n < 4; n++)
#pragma unroll
            for (int r = 0; r < 4; r++)
                sf[n][r] = fexp2(sf[n][r] - mrow[r]);
#pragma unroll
        for (int r = 0; r < 4; r++)  // lane-local partial sum; cross-lane deferred to end
            lrow[r] += (sf[0][r] + sf[1][r]) + (sf[2][r] + sf[3][r]);

        // ---- P -> LDS (wave-private rows), packed converts ----
        {
            const int pr0 = w * 16 + g4 * 4;
#pragma unroll
            for (int r = 0; r < 4; r++) {
                unsigned w01 = cvtpk_bf16(sf[0][r], sf[1][r]);
                unsigned w23 = cvtpk_bf16(sf[2][r], sf[3][r]);
                unsigned short* row = Plds + (pr0 + r) * 68;
                row[c15] = (unsigned short)w01;
                row[16 + c15] = (unsigned short)(w01 >> 16);
                row[32 + c15] = (unsigned short)w23;
                row[48 + c15] = (unsigned short)(w23 >> 16);
            }
        }
        asm volatile("s_waitcnt lgkmcnt(0)" ::: "memory");

        // ---- PV ----
        bf16x8 pf[2];
        {
            const unsigned short* pp = Plds + (w * 16 + c15) * 68 + kb8;
            pf[0] = *(const bf16x8*)pp;
            pf[1] = *(const bf16x8*)(pp + 32);
        }
        bf16x8 vf[4][2];
#pragma unroll
        for (int n = 0; n < 4; n++) {
            const int dc = n * 16 + c15;
            const char* vro = vb_l + dc * 128;
            const int sw = (dc & 7) << 4;
            vf[n][0] = *(const bf16x8*)(vro + ((kb8 * 2) ^ sw));
            vf[n][1] = *(const bf16x8*)(vro + ((kb8 * 2 + 64) ^ sw));
        }
        __builtin_amdgcn_s_setprio(1);
#pragma unroll
        for (int n = 0; n < 4; n++) {
            o[n] = mfma16(pf[0], vf[n][0], o[n]);
            o[n] = mfma16(pf[1], vf[n][1], o[n]);
        }
        __builtin_amdgcn_s_setprio(0);

        if (kt + 1 < 32) {
            asm volatile("s_waitcnt vmcnt(0)" ::: "memory");
            __syncthreads();
            cur ^= 1;
        }
    }

    // ---- finish deferred cross-lane l reduction ----
#pragma unroll
    for (int mask = 1; mask < 16; mask <<= 1)
#pragma unroll
        for (int r = 0; r < 4; r++)
            lrow[r] += __shfl_xor(lrow[r], mask);

    const int so0 = q0 + w * 16 + g4 * 4;
#pragma unroll
    for (int r = 0; r < 4; r++) {
        const float inv = 1.0f / lrow[r];
        float* op = out + ((size_t)b * S_ + so0 + r) * E_ + h * D_;
#pragma unroll
        for (int n = 0; n < 4; n++)
            op[n * 16 + c15] = o[n][r] * inv;
    }
}

extern "C" void kernel_launch(void* const* d_in, const int* in_sizes, int n_in,
                              void* d_out, int out_size, void* d_ws, size_t ws_size,
                              hipStream_t stream) {
    (void)in_sizes; (void)n_in; (void)out_size; (void)ws_size;
    const float* x = (const float*)d_in[0];
    const float* Wq = (const float*)d_in[1];
    const float* Wk = (const float*)d_in[2];
    const float* Wv = (const float*)d_in[3];
    const float* sqk = (const float*)d_in[4];
    const float* fcos = (const float*)d_in[5];
    const float* fsin = (const float*)d_in[6];

    char* ws = (char*)d_ws;
    size_t off = 0;
    unsigned short* xbf = (unsigned short*)(ws + off); off += (size_t)B_ * S_ * E_ * 2;
    unsigned short* wbf = (unsigned short*)(ws + off); off += (size_t)3 * E_ * E_ * 2;
    unsigned short* qws = (unsigned short*)(ws + off); off += (size_t)B_ * H_ * S_ * D_ * 2;
    unsigned short* kws = (unsigned short*)(ws + off); off += (size_t)B_ * H_ * S_ * D_ * 2;
    unsigned short* vtws = (unsigned short*)(ws + off); off += (size_t)B_ * H_ * S_ * D_ * 2;

    cvt_f32_bf16_k<<<dim3(2048), dim3(256), 0, stream>>>(x, xbf, (B_ * S_ * E_) / 4);
    cvt_f32_bf16_k<<<dim3(512), dim3(256), 0, stream>>>(Wq, wbf, (E_ * E_) / 4);
    cvt_f32_bf16_k<<<dim3(512), dim3(256), 0, stream>>>(Wk, wbf + E_ * E_, (E_ * E_) / 4);
    cvt_f32_bf16_k<<<dim3(512), dim3(256), 0, stream>>>(Wv, wbf + 2 * E_ * E_, (E_ * E_) / 4);

    qkv_gemm_k<<<dim3(24, 64), dim3(256), 0, stream>>>(xbf, wbf, sqk, fcos, fsin,
                                                       qws, kws, vtws);
    attn_fwd_k<<<dim3(2048), dim3(256), 0, stream>>>(qws, kws, vtws, (float*)d_out);
}

// Round 9
// 334.056 us; speedup vs baseline: 1.1735x; 1.0662x over previous
//
#include <hip/hip_runtime.h>
#include <stdint.h>

#define B_ 4
#define S_ 2048
#define H_ 16
#define D_ 64
#define E_ 1024

typedef __bf16 bf16x8 __attribute__((ext_vector_type(8)));
typedef float f32x4 __attribute__((ext_vector_type(4)));
typedef unsigned short u16x4 __attribute__((ext_vector_type(4)));

static __device__ __forceinline__ unsigned short f2bf(float f) {
    unsigned u = __builtin_bit_cast(unsigned, f);
    u += 0x7fffu + ((u >> 16) & 1u);
    return (unsigned short)(u >> 16);
}

static __device__ __forceinline__ float fexp2(float x) {
    float r;
    asm("v_exp_f32 %0, %1" : "=v"(r) : "v"(x));
    return r;
}

static __device__ __forceinline__ unsigned cvtpk_bf16(float lo, float hi) {
    unsigned r;
    asm("v_cvt_pk_bf16_f32 %0, %1, %2" : "=v"(r) : "v"(lo), "v"(hi));
    return r;
}

static __device__ __forceinline__ f32x4 mfma16(bf16x8 a, bf16x8 b, f32x4 c) {
    return __builtin_amdgcn_mfma_f32_16x16x32_bf16(a, b, c, 0, 0, 0);
}

static __device__ __forceinline__ void gload_lds16(const void* g, void* l) {
    __builtin_amdgcn_global_load_lds(
        (__attribute__((address_space(1))) void*)g,
        (__attribute__((address_space(3))) void*)l, 16, 0, 0);
}

// ---------------- fp32 -> bf16 convert ----------------
__global__ void cvt_f32_bf16_k(const float* __restrict__ src,
                               unsigned short* __restrict__ dst, int n4) {
    int stride = gridDim.x * blockDim.x;
    for (int i = blockIdx.x * blockDim.x + threadIdx.x; i < n4; i += stride) {
        float4 v = reinterpret_cast<const float4*>(src)[i];
        u16x4 o;
        o[0] = f2bf(v.x); o[1] = f2bf(v.y); o[2] = f2bf(v.z); o[3] = f2bf(v.w);
        reinterpret_cast<u16x4*>(dst)[i] = o;
    }
}

// ---------------- QKV projection GEMM (m97 structure) + fused RoPE/l2norm epilogue ----------------
// Q gets D^-0.5 * log2(e) folded in so attention can use raw exp2.
// setprio removed: lockstep 2-barrier GEMM gets no benefit (m190), cost ~10us.
__global__ __launch_bounds__(256) void qkv_gemm_k(
    const unsigned short* __restrict__ xbf,
    const unsigned short* __restrict__ wbf,
    const float* __restrict__ sqk,
    const float* __restrict__ fcos,
    const float* __restrict__ fsin,
    unsigned short* __restrict__ qws,
    unsigned short* __restrict__ kws,
    unsigned short* __restrict__ vtws)
{
    __shared__ unsigned short As[128 * 32];
    __shared__ unsigned short Bs[128 * 32];
    const int tid = threadIdx.x;
    const int w = tid >> 6, lane = tid & 63;
    const int wr = w >> 1, wc = w & 1;
    const int mbase = blockIdx.y * 128;
    const int nbase = blockIdx.x * 128;
    const int c15 = lane & 15;
    const int g4 = lane >> 4;
    const int kb8 = g4 * 8;

    const f32x4 zero4 = {0.f, 0.f, 0.f, 0.f};
    f32x4 acc[4][4];
#pragma unroll
    for (int m = 0; m < 4; m++)
#pragma unroll
        for (int n = 0; n < 4; n++) acc[m][n] = zero4;

    for (int kt = 0; kt < 32; ++kt) {
        const int k0 = kt * 32;
#pragma unroll
        for (int i = 0; i < 2; i++) {
            int g = (i * 4 + w) * 64 + lane;
            int row = g >> 2, slot = g & 3;
            gload_lds16(xbf + (size_t)(mbase + row) * E_ + k0 + slot * 8,
                        As + (i * 4 + w) * 512);
            gload_lds16(wbf + (size_t)(nbase + row) * E_ + k0 + slot * 8,
                        Bs + (i * 4 + w) * 512);
        }
        asm volatile("s_waitcnt vmcnt(0)" ::: "memory");
        __syncthreads();
        bf16x8 af[4], bfr[4];
#pragma unroll
        for (int m = 0; m < 4; m++)
            af[m] = *(const bf16x8*)(As + (wr * 64 + m * 16 + c15) * 32 + kb8);
#pragma unroll
        for (int n = 0; n < 4; n++)
            bfr[n] = *(const bf16x8*)(Bs + (wc * 64 + n * 16 + c15) * 32 + kb8);
#pragma unroll
        for (int m = 0; m < 4; m++)
#pragma unroll
            for (int n = 0; n < 4; n++)
                acc[m][n] = mfma16(af[m], bfr[n], acc[m][n]);
        __syncthreads();
    }

    // ---- epilogue ----
    const int gcb = nbase + wc * 64;
    const int qkv = gcb >> 10;
    const int oo = gcb & 1023;
    const int h = oo >> 6;

    if (qkv < 2) {
        unsigned short* dst = (qkv == 0) ? qws : kws;
        const float qs = (qkv == 0) ? (0.125f * 1.44269504f) : 1.0f;
        float cs4[4];
#pragma unroll
        for (int n = 0; n < 4; n++)
            cs4[n] = sqk[oo + n * 16 + c15] * 32.0f * qs;
#pragma unroll
        for (int m = 0; m < 4; m++) {
#pragma unroll
            for (int r = 0; r < 4; r++) {
                const int grow = mbase + wr * 64 + m * 16 + g4 * 4 + r;
                const int bb = grow >> 11;
                const int srow = grow & 2047;
                float nv[4], ss = 0.f;
#pragma unroll
                for (int n = 0; n < 4; n++) {
                    const int d = n * 16 + c15;
                    const float a = acc[m][n][r];
                    const float other = __shfl_xor(a, 1);
                    const float cc = fcos[srow * 32 + (d >> 1)];
                    const float sn = fsin[srow * 32 + (d >> 1)];
                    const float rv = (d & 1) ? (other * sn + a * cc) : (a * cc - other * sn);
                    nv[n] = rv;
                    ss += rv * rv;
                }
#pragma unroll
                for (int mask = 1; mask < 16; mask <<= 1)
                    ss += __shfl_xor(ss, mask);
                const float rn = rsqrtf(ss);
                unsigned short* rp = dst + ((size_t)(bb * H_ + h) * S_ + srow) * D_;
#pragma unroll
                for (int n = 0; n < 4; n++)
                    rp[n * 16 + c15] = f2bf(nv[n] * rn * cs4[n]);
            }
        }
    } else {
#pragma unroll
        for (int m = 0; m < 4; m++) {
            const int grow0 = mbase + wr * 64 + m * 16 + g4 * 4;
            const int bb = grow0 >> 11;
            const int srow0 = grow0 & 2047;
#pragma unroll
            for (int n = 0; n < 4; n++) {
                const int d = n * 16 + c15;
                u16x4 pk;
#pragma unroll
                for (int r = 0; r < 4; r++) pk[r] = f2bf(acc[m][n][r]);
                *reinterpret_cast<u16x4*>(vtws + ((size_t)(bb * H_ + h) * D_ + d) * S_ + srow0) = pk;
            }
        }
    }
}

// ---------------- flash attention: 8 waves, 128 q-rows/block ----------------
// Latency-bound fix: same KV dbuf LDS shared by 8 waves -> 24 waves/CU (6/SIMD)
// vs 12 before; per-wave STAGE work halves; KV refetch per q-row halves.
__global__ __launch_bounds__(512) void attn_fwd_k(
    const unsigned short* __restrict__ qws,
    const unsigned short* __restrict__ kws,
    const unsigned short* __restrict__ vtws,
    float* __restrict__ out)
{
    __shared__ unsigned short Klds[2 * 64 * 64];
    __shared__ unsigned short Vlds[2 * 64 * 64];
    __shared__ unsigned short Plds[128 * 68];  // pad 68: writes/reads <=2-way
    const int tid = threadIdx.x;
    const int w = tid >> 6, lane = tid & 63;
    const int c15 = lane & 15;
    const int g4 = lane >> 4;
    const int kb8 = g4 * 8;

    // XCD-aware swizzle: 1024 blocks = 8 xcd * (8 bh * 16 qtiles)
    const int id = blockIdx.x;
    const int xcd = id & 7, c = id >> 3;
    const int bh = xcd * 8 + (c >> 4);
    const int q0 = (c & 15) * 128;
    const int b = bh >> 4, h = bh & 15;

    bf16x8 qf[2];
    {
        const unsigned short* qp =
            qws + ((size_t)bh * S_ + (q0 + w * 16 + c15)) * D_ + kb8;
        qf[0] = *(const bf16x8*)qp;
        qf[1] = *(const bf16x8*)(qp + 32);
    }

    const f32x4 zero4 = {0.f, 0.f, 0.f, 0.f};
    float mrow[4], lrow[4];
    f32x4 o[4];
#pragma unroll
    for (int n = 0; n < 4; n++) o[n] = zero4;
#pragma unroll
    for (int r = 0; r < 4; r++) { mrow[r] = -3.0e38f; lrow[r] = 0.f; }

    const char* kbase_g = (const char*)(kws + (size_t)bh * S_ * D_);
    const unsigned short* vbase_g = vtws + (size_t)bh * D_ * S_;

    // 512 lanes x 16B = one full 8KB tile per STAGE call for each of K and V.
    auto STAGE = [&](int t, int bsel) {
        {
            int loff = (w * 64 + lane) * 16;
            int soff = loff ^ (((loff >> 7) & 7) << 4);
            gload_lds16(kbase_g + (size_t)t * 8192 + soff,
                        (char*)Klds + bsel * 8192 + w * 1024);
        }
        {
            int g = w * 64 + lane;
            int row = g >> 3, slot = g & 7;
            int soff = (slot * 16) ^ ((row & 7) << 4);
            gload_lds16((const char*)(vbase_g + (size_t)row * S_ + t * 64) + soff,
                        (char*)Vlds + bsel * 8192 + w * 1024);
        }
    };

    STAGE(0, 0);
    asm volatile("s_waitcnt vmcnt(0)" ::: "memory");
    __syncthreads();

    int cur = 0;
    for (int kt = 0; kt < 32; ++kt) {
        if (kt + 1 < 32) STAGE(kt + 1, cur ^ 1);  // prefetch next tile

        const char* kb_l = (const char*)Klds + cur * 8192;
        const char* vb_l = (const char*)Vlds + cur * 8192;

        // ---- QK^T ----
        f32x4 sf[4];
        bf16x8 kf[4][2];
#pragma unroll
        for (int n = 0; n < 4; n++) {
            const int kvc = n * 16 + c15;
            const char* kro = kb_l + kvc * 128;
            const int sw = (kvc & 7) << 4;
            kf[n][0] = *(const bf16x8*)(kro + ((kb8 * 2) ^ sw));
            kf[n][1] = *(const bf16x8*)(kro + ((kb8 * 2 + 64) ^ sw));
        }
        __builtin_amdgcn_s_setprio(1);
#pragma unroll
        for (int n = 0; n < 4; n++) {
            sf[n] = zero4;
            sf[n] = mfma16(qf[0], kf[n][0], sf[n]);
            sf[n] = mfma16(qf[1], kf[n][1], sf[n]);
        }
        __builtin_amdgcn_s_setprio(0);

        // ---- online softmax: defer-max (THR=8 in exp2 domain) ----
        float pmax[4];
#pragma unroll
        for (int r = 0; r < 4; r++)
            pmax[r] = fmaxf(fmaxf(sf[0][r], sf[1][r]), fmaxf(sf[2][r], sf[3][r]));
        int ok = (pmax[0] <= mrow[0] + 8.0f) & (pmax[1] <= mrow[1] + 8.0f) &
                 (pmax[2] <= mrow[2] + 8.0f) & (pmax[3] <= mrow[3] + 8.0f);
        if (!__all(ok)) {
#pragma unroll
            for (int r = 0; r < 4; r++) {
                float mn = pmax[r];
#pragma unroll
                for (int mask = 1; mask < 16; mask <<= 1)
                    mn = fmaxf(mn, __shfl_xor(mn, mask));
                float mt = fmaxf(mrow[r], mn);
                float al = fexp2(mrow[r] - mt);
                mrow[r] = mt;
                lrow[r] *= al;
#pragma unroll
                for (int n = 0; n < 4; n++) o[n][r] *= al;
            }
        }
#pragma unroll
        for (int n = 0; n < 4; n++)
#pragma unroll
            for (int r = 0; r < 4; r++)
                sf[n][r] = fexp2(sf[n][r] - mrow[r]);
#pragma unroll
        for (int r = 0; r < 4; r++)  // lane-local partial sum; cross-lane deferred to end
            lrow[r] += (sf[0][r] + sf[1][r]) + (sf[2][r] + sf[3][r]);

        // ---- P -> LDS (wave-private rows), packed converts ----
        {
            const int pr0 = w * 16 + g4 * 4;
#pragma unroll
            for (int r = 0; r < 4; r++) {
                unsigned w01 = cvtpk_bf16(sf[0][r], sf[1][r]);
                unsigned w23 = cvtpk_bf16(sf[2][r], sf[3][r]);
                unsigned short* row = Plds + (pr0 + r) * 68;
                row[c15] = (unsigned short)w01;
                row[16 + c15] = (unsigned short)(w01 >> 16);
                row[32 + c15] = (unsigned short)w23;
                row[48 + c15] = (unsigned short)(w23 >> 16);
            }
        }
        asm volatile("s_waitcnt lgkmcnt(0)" ::: "memory");

        // ---- PV ----
        bf16x8 pf[2];
        {
            const unsigned short* pp = Plds + (w * 16 + c15) * 68 + kb8;
            pf[0] = *(const bf16x8*)pp;
            pf[1] = *(const bf16x8*)(pp + 32);
        }
        bf16x8 vf[4][2];
#pragma unroll
        for (int n = 0; n < 4; n++) {
            const int dc = n * 16 + c15;
            const char* vro = vb_l + dc * 128;
            const int sw = (dc & 7) << 4;
            vf[n][0] = *(const bf16x8*)(vro + ((kb8 * 2) ^ sw));
            vf[n][1] = *(const bf16x8*)(vro + ((kb8 * 2 + 64) ^ sw));
        }
        __builtin_amdgcn_s_setprio(1);
#pragma unroll
        for (int n = 0; n < 4; n++) {
            o[n] = mfma16(pf[0], vf[n][0], o[n]);
            o[n] = mfma16(pf[1], vf[n][1], o[n]);
        }
        __builtin_amdgcn_s_setprio(0);

        if (kt + 1 < 32) {
            asm volatile("s_waitcnt vmcnt(0)" ::: "memory");
            __syncthreads();
            cur ^= 1;
        }
    }

    // ---- finish deferred cross-lane l reduction ----
#pragma unroll
    for (int mask = 1; mask < 16; mask <<= 1)
#pragma unroll
        for (int r = 0; r < 4; r++)
            lrow[r] += __shfl_xor(lrow[r], mask);

    const int so0 = q0 + w * 16 + g4 * 4;
#pragma unroll
    for (int r = 0; r < 4; r++) {
        const float inv = 1.0f / lrow[r];
        float* op = out + ((size_t)b * S_ + so0 + r) * E_ + h * D_;
#pragma unroll
        for (int n = 0; n < 4; n++)
            op[n * 16 + c15] = o[n][r] * inv;
    }
}

extern "C" void kernel_launch(void* const* d_in, const int* in_sizes, int n_in,
                              void* d_out, int out_size, void* d_ws, size_t ws_size,
                              hipStream_t stream) {
    (void)in_sizes; (void)n_in; (void)out_size; (void)ws_size;
    const float* x = (const float*)d_in[0];
    const float* Wq = (const float*)d_in[1];
    const float* Wk = (const float*)d_in[2];
    const float* Wv = (const float*)d_in[3];
    const float* sqk = (const float*)d_in[4];
    const float* fcos = (const float*)d_in[5];
    const float* fsin = (const float*)d_in[6];

    char* ws = (char*)d_ws;
    size_t off = 0;
    unsigned short* xbf = (unsigned short*)(ws + off); off += (size_t)B_ * S_ * E_ * 2;
    unsigned short* wbf = (unsigned short*)(ws + off); off += (size_t)3 * E_ * E_ * 2;
    unsigned short* qws = (unsigned short*)(ws + off); off += (size_t)B_ * H_ * S_ * D_ * 2;
    unsigned short* kws = (unsigned short*)(ws + off); off += (size_t)B_ * H_ * S_ * D_ * 2;
    unsigned short* vtws = (unsigned short*)(ws + off); off += (size_t)B_ * H_ * S_ * D_ * 2;

    cvt_f32_bf16_k<<<dim3(2048), dim3(256), 0, stream>>>(x, xbf, (B_ * S_ * E_) / 4);
    cvt_f32_bf16_k<<<dim3(512), dim3(256), 0, stream>>>(Wq, wbf, (E_ * E_) / 4);
    cvt_f32_bf16_k<<<dim3(512), dim3(256), 0, stream>>>(Wk, wbf + E_ * E_, (E_ * E_) / 4);
    cvt_f32_bf16_k<<<dim3(512), dim3(256), 0, stream>>>(Wv, wbf + 2 * E_ * E_, (E_ * E_) / 4);

    qkv_gemm_k<<<dim3(24, 64), dim3(256), 0, stream>>>(xbf, wbf, sqk, fcos, fsin,
                                                       qws, kws, vtws);
    attn_fwd_k<<<dim3(1024), dim3(512), 0, stream>>>(qws, kws, vtws, (float*)d_out);
}